// Round 1
// baseline (1517.173 us; speedup 1.0000x reference)
//
#include <hip/hip_runtime.h>

// GCN: h1 = relu(GCNConv(x,W1,b1)); h2 = relu(GCNConv(h1,W2,b2));
// g = max over nodes; out = log_softmax(g@fcW + fcb)
// GCNConv(v) = dinv[v]*( sum_{u->v} h[u]*dinv[u] + h[v]*dinv[v] ) + b
// where deg[v] = in_degree(v)+1, dinv = rsqrt(deg).

#define TPB 256

__global__ void k_count_deg(const int* __restrict__ dst, float* __restrict__ deg, int E) {
    int t = blockIdx.x * blockDim.x + threadIdx.x;
    if (t < E) atomicAdd(&deg[dst[t]], 1.0f);
}

__global__ void k_dinv(float* __restrict__ deg, int N) {
    int t = blockIdx.x * blockDim.x + threadIdx.x;
    if (t < N) deg[t] = rsqrtf(deg[t] + 1.0f);
}

// A[v*32+f] = (x[v,:8] @ W1[:, f]) * dinv[v]
__global__ void k_xw1(const float* __restrict__ x, const float* __restrict__ W1,
                      const float* __restrict__ dinv, float* __restrict__ A, int N) {
    __shared__ float sW[8 * 32];
    int tid = threadIdx.x;
    sW[tid] = W1[tid];            // blockDim == 256 == 8*32
    __syncthreads();
    int gid = blockIdx.x * blockDim.x + tid;
    if (gid >= N * 32) return;
    int v = gid >> 5, f = gid & 31;
    const float* xr = x + v * 8;
    float s = 0.f;
#pragma unroll
    for (int k = 0; k < 8; ++k) s += xr[k] * sW[k * 32 + f];
    A[gid] = s * dinv[v];
}

// B[v*32+f] = (A[v,:32] @ W2[:, f]) * dinv[v]
__global__ void k_xw2(const float* __restrict__ A, const float* __restrict__ W2,
                      const float* __restrict__ dinv, float* __restrict__ B, int N) {
    __shared__ float sW[32 * 32];
    int tid = threadIdx.x;
#pragma unroll
    for (int i = tid; i < 1024; i += TPB) sW[i] = W2[i];
    __syncthreads();
    int gid = blockIdx.x * blockDim.x + tid;
    if (gid >= N * 32) return;
    int v = gid >> 5, f = gid & 31;
    const float* ar = A + v * 32;
    float s = 0.f;
#pragma unroll
    for (int k = 0; k < 32; ++k) s += ar[k] * sW[k * 32 + f];
    B[gid] = s * dinv[v];
}

// Agg[dst] += Hs[src]  (32 floats per edge; 8 threads/edge, float4 each)
__global__ void k_agg(const float* __restrict__ Hs, float* __restrict__ Agg,
                      const int* __restrict__ src, const int* __restrict__ dst, int E) {
    int t = blockIdx.x * blockDim.x + threadIdx.x;
    if (t >= E * 8) return;
    int e = t >> 3, q = t & 7;
    int s = src[e], d = dst[e];
    float4 val = ((const float4*)Hs)[s * 8 + q];
    float* bp = Agg + (size_t)d * 32 + q * 4;
    atomicAdd(bp + 0, val.x);
    atomicAdd(bp + 1, val.y);
    atomicAdd(bp + 2, val.z);
    atomicAdd(bp + 3, val.w);
}

// A[gid] = relu(dinv[v]*(A[gid]+B[gid]) + b[f])   (in place, elementwise)
__global__ void k_fin1(float* __restrict__ A, const float* __restrict__ B,
                       const float* __restrict__ dinv, const float* __restrict__ b, int N) {
    int gid = blockIdx.x * blockDim.x + threadIdx.x;
    if (gid >= N * 32) return;
    int v = gid >> 5, f = gid & 31;
    A[gid] = fmaxf(dinv[v] * (A[gid] + B[gid]) + b[f], 0.f);
}

// val = relu(dinv[v]*(Agg[i]+Hs[i]) + b2[f]); global max per feature.
// m starts at 0 so relu is implicit. Post-relu values >= 0 so uint-bit
// atomicMax is order-equivalent to float max; gmax zero-init == 0.0f.
__global__ void k_fin2max(const float* __restrict__ Agg, const float* __restrict__ Hs,
                          const float* __restrict__ dinv, const float* __restrict__ b,
                          unsigned* __restrict__ gmax, int N) {
    int tid = threadIdx.x;
    int f = tid & 31;
    float bb = b[f];
    float m = 0.f;
    int total = N * 32;
    int stride = gridDim.x * blockDim.x;   // multiple of 32 -> f fixed per thread
    for (int i = blockIdx.x * blockDim.x + tid; i < total; i += stride) {
        int v = i >> 5;
        m = fmaxf(m, dinv[v] * (Agg[i] + Hs[i]) + bb);
    }
    __shared__ float red[TPB];
    red[tid] = m;
    __syncthreads();
    for (int off = 128; off >= 32; off >>= 1) {
        if (tid < off) red[tid] = fmaxf(red[tid], red[tid + off]);
        __syncthreads();
    }
    if (tid < 32) atomicMax(&gmax[tid], __float_as_uint(red[tid]));
}

__global__ void k_head(const unsigned* __restrict__ gmax, const float* __restrict__ fcW,
                       const float* __restrict__ fcb, float* __restrict__ out) {
    if (threadIdx.x != 0 || blockIdx.x != 0) return;
    float g[32];
#pragma unroll
    for (int f = 0; f < 32; ++f) g[f] = __uint_as_float(gmax[f]);
    float logit[5];
    float mx = -1e30f;
#pragma unroll
    for (int c = 0; c < 5; ++c) {
        float s = fcb[c];
#pragma unroll
        for (int f = 0; f < 32; ++f) s += g[f] * fcW[f * 5 + c];
        logit[c] = s;
        mx = fmaxf(mx, s);
    }
    float lse = 0.f;
#pragma unroll
    for (int c = 0; c < 5; ++c) lse += expf(logit[c] - mx);
    lse = logf(lse) + mx;
#pragma unroll
    for (int c = 0; c < 5; ++c) out[c] = logit[c] - lse;
}

static inline size_t align256(size_t x) { return (x + 255) & ~size_t(255); }

extern "C" void kernel_launch(void* const* d_in, const int* in_sizes, int n_in,
                              void* d_out, int out_size, void* d_ws, size_t ws_size,
                              hipStream_t stream) {
    const float* x   = (const float*)d_in[0];
    const int*   ei  = (const int*)d_in[1];
    const float* W1  = (const float*)d_in[2];
    const float* b1  = (const float*)d_in[3];
    const float* W2  = (const float*)d_in[4];
    const float* b2  = (const float*)d_in[5];
    const float* fcW = (const float*)d_in[6];
    const float* fcb = (const float*)d_in[7];
    float* out = (float*)d_out;

    const int N = in_sizes[0] / 8;
    const int E = in_sizes[1] / 2;
    const int* src = ei;
    const int* dst = ei + E;

    char* ws = (char*)d_ws;
    size_t off = 0;
    float* dinv = (float*)(ws + off); off += align256((size_t)N * 4);
    float* A    = (float*)(ws + off); off += align256((size_t)N * 32 * 4);
    float* B    = (float*)(ws + off); off += align256((size_t)N * 32 * 4);
    unsigned* gmax = (unsigned*)(ws + off);

    const int NF = N * 32;
    dim3 blk(TPB);

    // zero scratch (ws is poisoned before every call)
    hipMemsetAsync(dinv, 0, (size_t)N * 4, stream);
    hipMemsetAsync(B, 0, (size_t)NF * 4, stream);
    hipMemsetAsync(gmax, 0, 32 * 4, stream);

    // degrees -> dinv
    k_count_deg<<<dim3((E + TPB - 1) / TPB), blk, 0, stream>>>(dst, dinv, E);
    k_dinv<<<dim3((N + TPB - 1) / TPB), blk, 0, stream>>>(dinv, N);

    // ---- layer 1 ----
    k_xw1<<<dim3((NF + TPB - 1) / TPB), blk, 0, stream>>>(x, W1, dinv, A, N);
    k_agg<<<dim3((E * 8 + TPB - 1) / TPB), blk, 0, stream>>>(A, B, src, dst, E);
    k_fin1<<<dim3((NF + TPB - 1) / TPB), blk, 0, stream>>>(A, B, dinv, b1, N);

    // ---- layer 2 ----
    k_xw2<<<dim3((NF + TPB - 1) / TPB), blk, 0, stream>>>(A, W2, dinv, B, N);
    hipMemsetAsync(A, 0, (size_t)NF * 4, stream);   // reuse A as agg2
    k_agg<<<dim3((E * 8 + TPB - 1) / TPB), blk, 0, stream>>>(B, A, src, dst, E);

    // ---- finalize layer2 + global max pool ----
    k_fin2max<<<dim3(512), blk, 0, stream>>>(A, B, dinv, b2, gmax, N);

    // ---- FC + log_softmax ----
    k_head<<<dim3(1), dim3(64), 0, stream>>>(gmax, fcW, fcb, out);
}

// Round 2
// 450.634 us; speedup vs baseline: 3.3667x; 3.3667x over previous
//
#include <hip/hip_runtime.h>

// GCN: h1 = relu(GCNConv(x,W1,b1)); h2 = relu(GCNConv(h1,W2,b2));
// g = max over nodes; out = log_softmax(g@fcW + fcb)
// GCNConv(v) = dinv[v]*( sum_{u->v} Hs[u] + Hs[v] ) + b,  Hs[u] = (h[u]@W)*dinv[u]
// deg[v] = in_degree(v)+1, dinv = rsqrt(deg).
//
// Round 2: scatter-atomics (800 MB WRITE_SIZE per k_agg) replaced by CSR-by-dst
// build + gather aggregation. No float atomics anywhere.

#define TPB 256
#define SCAN_TPB 256
#define SCAN_ITEMS 8
#define SCAN_CHUNK 2048   // SCAN_TPB * SCAN_ITEMS = 2^11

// ---- CSR build -------------------------------------------------------------

__global__ void k_hist(const int* __restrict__ dst, int* __restrict__ cnt, int E) {
    int t = blockIdx.x * blockDim.x + threadIdx.x;
    if (t < E) atomicAdd(&cnt[dst[t]], 1);
}

// per-block exclusive scan of cnt -> rowptr, block totals -> blockSums
__global__ void k_scan1(const int* __restrict__ cnt, int* __restrict__ rowptr,
                        int* __restrict__ blockSums, int N) {
    __shared__ int sums[SCAN_TPB];
    int tid = threadIdx.x;
    int base = blockIdx.x * SCAN_CHUNK + tid * SCAN_ITEMS;
    int loc[SCAN_ITEMS];
    int s = 0;
#pragma unroll
    for (int i = 0; i < SCAN_ITEMS; ++i) {
        int idx = base + i;
        int c = (idx < N) ? cnt[idx] : 0;
        loc[i] = s;
        s += c;
    }
    sums[tid] = s;
    __syncthreads();
    for (int off = 1; off < SCAN_TPB; off <<= 1) {
        int v = (tid >= off) ? sums[tid - off] : 0;
        __syncthreads();
        sums[tid] += v;
        __syncthreads();
    }
    int excl = (tid > 0) ? sums[tid - 1] : 0;
#pragma unroll
    for (int i = 0; i < SCAN_ITEMS; ++i) {
        int idx = base + i;
        if (idx < N) rowptr[idx] = excl + loc[i];
    }
    if (tid == SCAN_TPB - 1) blockSums[blockIdx.x] = sums[tid];
}

// exclusive scan of block sums (single block; NB <= 64)
__global__ void k_scan2(int* __restrict__ blockSums, int NB) {
    __shared__ int s[64];
    int tid = threadIdx.x;
    s[tid] = (tid < NB) ? blockSums[tid] : 0;
    __syncthreads();
    for (int off = 1; off < 64; off <<= 1) {
        int v = (tid >= off) ? s[tid - off] : 0;
        __syncthreads();
        s[tid] += v;
        __syncthreads();
    }
    if (tid < NB) blockSums[tid] = (tid > 0) ? s[tid - 1] : 0;
}

// add block offsets; init cursor; compute dinv; write rowptr[N]=E
__global__ void k_scan3(int* __restrict__ rowptr, const int* __restrict__ blockSums,
                        const int* __restrict__ cnt, int* __restrict__ cursor,
                        float* __restrict__ dinv, int N, int E) {
    int i = blockIdx.x * blockDim.x + threadIdx.x;
    if (i < N) {
        int r = rowptr[i] + blockSums[i >> 11];
        rowptr[i] = r;
        cursor[i] = r;
        dinv[i] = rsqrtf((float)cnt[i] + 1.0f);
    } else if (i == N) {
        rowptr[N] = E;
    }
}

__global__ void k_scatter(const int* __restrict__ src, const int* __restrict__ dst,
                          int* __restrict__ cursor, int* __restrict__ adj, int E) {
    int e = blockIdx.x * blockDim.x + threadIdx.x;
    if (e < E) {
        int d = dst[e];
        int pos = atomicAdd(&cursor[d], 1);
        adj[pos] = src[e];
    }
}

// ---- dense transforms ------------------------------------------------------

// A[v*32+f] = (x[v,:8] @ W1[:, f]) * dinv[v]
__global__ void k_xw1(const float* __restrict__ x, const float* __restrict__ W1,
                      const float* __restrict__ dinv, float* __restrict__ A, int N) {
    __shared__ float sW[8 * 32];
    int tid = threadIdx.x;
    sW[tid] = W1[tid];            // blockDim == 256 == 8*32
    __syncthreads();
    int gid = blockIdx.x * blockDim.x + tid;
    if (gid >= N * 32) return;
    int v = gid >> 5, f = gid & 31;
    const float* xr = x + v * 8;
    float s = 0.f;
#pragma unroll
    for (int k = 0; k < 8; ++k) s += xr[k] * sW[k * 32 + f];
    A[gid] = s * dinv[v];
}

// B[v*32+f] = (H1[v,:32] @ W2[:, f]) * dinv[v]
__global__ void k_xw2(const float* __restrict__ H1, const float* __restrict__ W2,
                      const float* __restrict__ dinv, float* __restrict__ B, int N) {
    __shared__ float sW[32 * 32];
    int tid = threadIdx.x;
#pragma unroll
    for (int i = tid; i < 1024; i += TPB) sW[i] = W2[i];
    __syncthreads();
    int gid = blockIdx.x * blockDim.x + tid;
    if (gid >= N * 32) return;
    int v = gid >> 5, f = gid & 31;
    const float* ar = H1 + v * 32;
    float s = 0.f;
#pragma unroll
    for (int k = 0; k < 32; ++k) s += ar[k] * sW[k * 32 + f];
    B[gid] = s * dinv[v];
}

// ---- gather aggregation ----------------------------------------------------

// Hout[v] = relu(dinv[v]*(sum_{u->v} Hs[u] + Hs[v]) + b). 8 threads/node, float4 each.
__global__ void k_gather1(const float* __restrict__ Hs, const int* __restrict__ rowptr,
                          const int* __restrict__ adj, const float* __restrict__ dinv,
                          const float* __restrict__ b, float* __restrict__ Hout, int N) {
    int t = blockIdx.x * blockDim.x + threadIdx.x;
    if (t >= N * 8) return;
    int v = t >> 3, q = t & 7;
    int beg = rowptr[v], end = rowptr[v + 1];
    float4 acc = ((const float4*)Hs)[(size_t)v * 8 + q];   // self-loop term
    for (int j = beg; j < end; ++j) {
        int s = adj[j];
        float4 xv = ((const float4*)Hs)[(size_t)s * 8 + q];
        acc.x += xv.x; acc.y += xv.y; acc.z += xv.z; acc.w += xv.w;
    }
    float dv = dinv[v];
    float4 bb = ((const float4*)b)[q];
    float4 r;
    r.x = fmaxf(dv * acc.x + bb.x, 0.f);
    r.y = fmaxf(dv * acc.y + bb.y, 0.f);
    r.z = fmaxf(dv * acc.z + bb.z, 0.f);
    r.w = fmaxf(dv * acc.w + bb.w, 0.f);
    ((float4*)Hout)[(size_t)v * 8 + q] = r;
}

// layer-2 gather fused with global max pool. Grid-stride over nodes; post-relu
// values >= 0 so uint-bit atomicMax with 0-init is exact float max.
__global__ void k_gather2max(const float* __restrict__ Hs, const int* __restrict__ rowptr,
                             const int* __restrict__ adj, const float* __restrict__ dinv,
                             const float* __restrict__ b, unsigned* __restrict__ gmax, int N) {
    int tid = threadIdx.x;
    int q = tid & 7;
    float4 bb = ((const float4*)b)[q];
    float4 m = make_float4(0.f, 0.f, 0.f, 0.f);   // relu floor folded in
    int groups = (gridDim.x * blockDim.x) >> 3;
    for (int v = (blockIdx.x * blockDim.x + tid) >> 3; v < N; v += groups) {
        int beg = rowptr[v], end = rowptr[v + 1];
        float4 acc = ((const float4*)Hs)[(size_t)v * 8 + q];
        for (int j = beg; j < end; ++j) {
            int s = adj[j];
            float4 xv = ((const float4*)Hs)[(size_t)s * 8 + q];
            acc.x += xv.x; acc.y += xv.y; acc.z += xv.z; acc.w += xv.w;
        }
        float dv = dinv[v];
        m.x = fmaxf(m.x, dv * acc.x + bb.x);
        m.y = fmaxf(m.y, dv * acc.y + bb.y);
        m.z = fmaxf(m.z, dv * acc.z + bb.z);
        m.w = fmaxf(m.w, dv * acc.w + bb.w);
    }
    __shared__ float4 red[TPB];
    red[tid] = m;
    __syncthreads();
    for (int off = 128; off >= 8; off >>= 1) {
        if (tid < off) {
            float4 o = red[tid + off], c = red[tid];
            c.x = fmaxf(c.x, o.x); c.y = fmaxf(c.y, o.y);
            c.z = fmaxf(c.z, o.z); c.w = fmaxf(c.w, o.w);
            red[tid] = c;
        }
        __syncthreads();
    }
    if (tid < 8) {
        float4 r = red[tid];
        atomicMax(&gmax[tid * 4 + 0], __float_as_uint(r.x));
        atomicMax(&gmax[tid * 4 + 1], __float_as_uint(r.y));
        atomicMax(&gmax[tid * 4 + 2], __float_as_uint(r.z));
        atomicMax(&gmax[tid * 4 + 3], __float_as_uint(r.w));
    }
}

// ---- head ------------------------------------------------------------------

__global__ void k_head(const unsigned* __restrict__ gmax, const float* __restrict__ fcW,
                       const float* __restrict__ fcb, float* __restrict__ out) {
    if (threadIdx.x != 0 || blockIdx.x != 0) return;
    float g[32];
#pragma unroll
    for (int f = 0; f < 32; ++f) g[f] = __uint_as_float(gmax[f]);
    float logit[5];
    float mx = -1e30f;
#pragma unroll
    for (int c = 0; c < 5; ++c) {
        float s = fcb[c];
#pragma unroll
        for (int f = 0; f < 32; ++f) s += g[f] * fcW[f * 5 + c];
        logit[c] = s;
        mx = fmaxf(mx, s);
    }
    float lse = 0.f;
#pragma unroll
    for (int c = 0; c < 5; ++c) lse += expf(logit[c] - mx);
    lse = logf(lse) + mx;
#pragma unroll
    for (int c = 0; c < 5; ++c) out[c] = logit[c] - lse;
}

static inline size_t align256(size_t x) { return (x + 255) & ~size_t(255); }

extern "C" void kernel_launch(void* const* d_in, const int* in_sizes, int n_in,
                              void* d_out, int out_size, void* d_ws, size_t ws_size,
                              hipStream_t stream) {
    const float* x   = (const float*)d_in[0];
    const int*   ei  = (const int*)d_in[1];
    const float* W1  = (const float*)d_in[2];
    const float* b1  = (const float*)d_in[3];
    const float* W2  = (const float*)d_in[4];
    const float* b2  = (const float*)d_in[5];
    const float* fcW = (const float*)d_in[6];
    const float* fcb = (const float*)d_in[7];
    float* out = (float*)d_out;

    const int N = in_sizes[0] / 8;
    const int E = in_sizes[1] / 2;
    const int* src = ei;
    const int* dst = ei + E;

    char* ws = (char*)d_ws;
    size_t off = 0;
    int*   cnt     = (int*)(ws + off);  off += align256((size_t)N * 4);
    int*   rowptr  = (int*)(ws + off);  off += align256((size_t)(N + 1) * 4);
    int*   cursor  = (int*)(ws + off);  off += align256((size_t)N * 4);
    int*   bsums   = (int*)(ws + off);  off += align256(64 * 4);
    float* dinv    = (float*)(ws + off); off += align256((size_t)N * 4);
    int*   adj     = (int*)(ws + off);  off += align256((size_t)E * 4);
    float* A       = (float*)(ws + off); off += align256((size_t)N * 32 * 4);
    float* B       = (float*)(ws + off); off += align256((size_t)N * 32 * 4);
    unsigned* gmax = (unsigned*)(ws + off);

    const int NF = N * 32;
    const int NB = (N + SCAN_CHUNK - 1) / SCAN_CHUNK;   // 49 for N=100000
    dim3 blk(TPB);

    hipMemsetAsync(cnt, 0, (size_t)N * 4, stream);
    hipMemsetAsync(gmax, 0, 32 * 4, stream);

    // ---- CSR build (by dst) ----
    k_hist<<<dim3((E + TPB - 1) / TPB), blk, 0, stream>>>(dst, cnt, E);
    k_scan1<<<dim3(NB), dim3(SCAN_TPB), 0, stream>>>(cnt, rowptr, bsums, N);
    k_scan2<<<dim3(1), dim3(64), 0, stream>>>(bsums, NB);
    k_scan3<<<dim3((N + TPB) / TPB), blk, 0, stream>>>(rowptr, bsums, cnt, cursor, dinv, N, E);
    k_scatter<<<dim3((E + TPB - 1) / TPB), blk, 0, stream>>>(src, dst, cursor, adj, E);

    // ---- layer 1 ----
    k_xw1<<<dim3((NF + TPB - 1) / TPB), blk, 0, stream>>>(x, W1, dinv, A, N);
    k_gather1<<<dim3((N * 8 + TPB - 1) / TPB), blk, 0, stream>>>(A, rowptr, adj, dinv, b1, B, N);

    // ---- layer 2 ----
    k_xw2<<<dim3((NF + TPB - 1) / TPB), blk, 0, stream>>>(B, W2, dinv, A, N);
    k_gather2max<<<dim3(1024), blk, 0, stream>>>(A, rowptr, adj, dinv, b2, gmax, N);

    // ---- FC + log_softmax ----
    k_head<<<dim3(1), dim3(64), 0, stream>>>(gmax, fcW, fcb, out);
}